// Round 3
// baseline (15201.875 us; speedup 1.0000x reference)
//
#include <hip/hip_runtime.h>
#include <hip/hip_bf16.h>
#include <cstdint>

// ---------------------------------------------------------------------------
// 2-layer LSTM, SEQ=512 B=64 IN=512 HID=1024.
// R3: persistent cooperative recurrence kernel (1 launch per layer, 512 steps
// inside, custom grid sync). w_hh in registers (128 VGPR/wave, loaded once),
// c state in registers, gates lane-local via row permutation m = hid*4+gate.
// Grid sync: release atomicAdd + relaxed poll + final ACQUIRE atomic load
// (no __hip_atomic_fence on this ROCm — acquire load synchronizes-with the
// release add).
// ---------------------------------------------------------------------------

typedef __attribute__((ext_vector_type(8))) short short8;    // 8 bf16
typedef __attribute__((ext_vector_type(4))) short short4b;   // 4 bf16
typedef __attribute__((ext_vector_type(4))) float f32x4;

#define AS1 __attribute__((address_space(1)))
#define AS3 __attribute__((address_space(3)))

static __device__ __forceinline__ void gload_lds16(const void* g, void* l) {
  __builtin_amdgcn_global_load_lds((const AS1 unsigned int*)g, (AS3 unsigned int*)l,
                                   16, 0, 0);
}

static __device__ __forceinline__ float sigmoidf_(float x) {
  return 1.f / (1.f + __expf(-x));
}

static __device__ __forceinline__ float bf2f(short s) {
  union { unsigned u; float f; } v;
  v.u = ((unsigned)(unsigned short)s) << 16;
  return v.f;
}

// --------------------------- f32 -> bf16 convert ---------------------------
__global__ void cvt_bf16(const float* __restrict__ in, __hip_bfloat16* __restrict__ out,
                         int n4) {
  int i = blockIdx.x * 256 + threadIdx.x;
  if (i >= n4) return;
  float4 v = ((const float4*)in)[i];
  out[i * 4 + 0] = __float2bfloat16(v.x);
  out[i * 4 + 1] = __float2bfloat16(v.y);
  out[i * 4 + 2] = __float2bfloat16(v.z);
  out[i * 4 + 3] = __float2bfloat16(v.w);
}

// --------------- f32 -> bf16 with gate-row permutation ---------------------
// out[(hid*4+g)*K + k] = in[(g*1024+hid)*K + k]
__global__ void cvt_permrow(const float* __restrict__ in, __hip_bfloat16* __restrict__ out,
                            int K) {
  int k4 = blockIdx.x * 256 + threadIdx.x;
  if (k4 >= (K >> 2)) return;
  int rp = blockIdx.y;                     // permuted row: hid*4+g
  int src = (rp & 3) * 1024 + (rp >> 2);
  float4 v = ((const float4*)(in + (size_t)src * K))[k4];
  __hip_bfloat16* o = out + (size_t)rp * K + k4 * 4;
  o[0] = __float2bfloat16(v.x);
  o[1] = __float2bfloat16(v.y);
  o[2] = __float2bfloat16(v.z);
  o[3] = __float2bfloat16(v.w);
}

// ------------------ bias sum with gate-row permutation ---------------------
__global__ void bias_perm(const float* __restrict__ b1, const float* __restrict__ b2,
                          float* __restrict__ o) {
  int i = blockIdx.x * 256 + threadIdx.x;  // i = hid*4+g
  if (i >= 4096) return;
  int src = (i & 3) * 1024 + (i >> 2);
  o[i] = b1[src] + b2[src];
}

// ------------------------------ state init --------------------------------
__global__ void init_state(const float* __restrict__ h0, const float* __restrict__ c0,
                           __hip_bfloat16* __restrict__ h_init, float* __restrict__ c_state,
                           int n) {
  int i = blockIdx.x * 256 + threadIdx.x;
  if (i >= n) return;
  h_init[i] = __float2bfloat16(h0[i]);
  c_state[i] = c0[i];
}

// ------------------------------- finalize ---------------------------------
__global__ void finalize_out(const float* __restrict__ hf, const float* __restrict__ cst,
                             float* __restrict__ out_h, float* __restrict__ out_c, int n) {
  int i = blockIdx.x * 256 + threadIdx.x;
  if (i >= n) return;
  out_h[i] = hf[i];
  out_c[i] = cst[i];
}

// --------------------- big GEMM: C = A @ B^T + bias ------------------------
// A: [M,K] bf16 row-major, B: [N,K] bf16 row-major (gate-permuted), C: [M,N] bf16.
__global__ __launch_bounds__(256) void gemm_bt_bias(
    const __hip_bfloat16* __restrict__ A, const __hip_bfloat16* __restrict__ B,
    __hip_bfloat16* __restrict__ C, const float* __restrict__ bias, int K, int N) {
  const int tid = threadIdx.x;
  const int lane = tid & 63;
  const int wv = tid >> 6;
  const int l15 = lane & 15, l4 = lane >> 4;
  const int bm = blockIdx.x * 128;
  const int bn = blockIdx.y * 128;
  __shared__ alignas(16) __hip_bfloat16 As[128 * 64];
  __shared__ alignas(16) __hip_bfloat16 Bs[128 * 64];
  f32x4 acc[4][4] = {};
  const int wm = (wv >> 1) * 64;
  const int wn = (wv & 1) * 64;

  for (int kt = 0; kt < K; kt += 64) {
    if (kt) __syncthreads();
#pragma unroll
    for (int it = 0; it < 4; ++it) {
      int ci = it * 256 + tid;
      int row = ci >> 3, c8 = ci & 7;
      gload_lds16(A + (bm + row) * K + kt + c8 * 8, As + (it * 256 + wv * 64) * 8);
      gload_lds16(B + (bn + row) * K + kt + c8 * 8, Bs + (it * 256 + wv * 64) * 8);
    }
    __syncthreads();
#pragma unroll
    for (int kk = 0; kk < 64; kk += 32) {
      short8 a[4], b[4];
#pragma unroll
      for (int m = 0; m < 4; ++m)
        a[m] = *(const short8*)(As + (wm + m * 16 + l15) * 64 + kk + l4 * 8);
#pragma unroll
      for (int n = 0; n < 4; ++n)
        b[n] = *(const short8*)(Bs + (wn + n * 16 + l15) * 64 + kk + l4 * 8);
#pragma unroll
      for (int m = 0; m < 4; ++m)
#pragma unroll
        for (int n = 0; n < 4; ++n)
          acc[m][n] = __builtin_amdgcn_mfma_f32_16x16x32_bf16(a[m], b[n], acc[m][n], 0, 0, 0);
    }
  }
#pragma unroll
  for (int n = 0; n < 4; ++n) {
    int col = bn + wn + n * 16 + l15;
    float bs = bias[col];
#pragma unroll
    for (int m = 0; m < 4; ++m) {
#pragma unroll
      for (int j = 0; j < 4; ++j) {
        int row = bm + wm + m * 16 + l4 * 4 + j;
        C[(size_t)row * N + col] = __float2bfloat16(acc[m][n][j] + bs);
      }
    }
  }
}

// ----------------------- persistent LSTM layer kernel ----------------------
// 128 blocks x 512 threads (8 waves). Wave = (row-strip, batch-strip):
//   hs = blockIdx.x*8 + (wv>>2)*4  (4 hidden units), bs = (wv&3)*16 (16 batch).
// A-frag rows (m=0..15) map to w_hh row (m&3)*1024 + hs + (m>>2), so D element
// j of lane (l4,l15) = gate j of hidden hs+l4, batch bs+l15: cell update is
// lane-local; c lives in one VGPR across all 512 steps. w_hh strip lives in
// 128 VGPRs, loaded once.
__global__ __launch_bounds__(512, 2) void lstm_persistent(
    const __hip_bfloat16* __restrict__ Gin,   // [512][64][4096] gate-permuted
    const __hip_bfloat16* __restrict__ Whh,   // [4096][1024]
    const __hip_bfloat16* __restrict__ h0b,   // [64][1024] initial h
    __hip_bfloat16* __restrict__ hist,        // h ring/history, stride 65536/t
    int tmask,                                // 511 = full history, 1 = ring
    float* __restrict__ cst,                  // [64][1024] c in/out
    float* __restrict__ y,                    // [512][64][1024] f32 or null
    float* __restrict__ hf,                   // [64][1024] final h f32
    unsigned* __restrict__ ctr) {
  const int tid = threadIdx.x;
  const int lane = tid & 63;
  const int wv = tid >> 6;
  const int l15 = lane & 15, l4 = lane >> 4;
  const int hs = blockIdx.x * 8 + (wv >> 2) * 4;
  const int bs = (wv & 3) * 16;
  const int bat = bs + l15;
  const int hid = hs + l4;
  const unsigned nb = gridDim.x;

  // ---- load w_hh strip into registers (resident across all steps) ----
  const int grow = (l15 & 3) * 1024 + hs + (l15 >> 2);
  const __hip_bfloat16* wrow = Whh + (size_t)grow * 1024 + l4 * 8;
  short8 a[32];
#pragma unroll
  for (int kk = 0; kk < 32; ++kk)
    a[kk] = *(const short8*)(wrow + kk * 32);

  float c = cst[bat * 1024 + hid];

  for (int t = 0; t < 512; ++t) {
    const __hip_bfloat16* hrow =
        (t ? hist + (size_t)((t - 1) & tmask) * 65536 : h0b) + bat * 1024 + l4 * 8;
    // gate preactivations (4 gates contiguous, 8B) — hidden under MFMAs
    short4b gv = *(const short4b*)(Gin + (size_t)t * 262144 + bat * 4096 + hid * 4);
    f32x4 acc[4] = {};
#pragma unroll
    for (int kk = 0; kk < 32; ++kk) {
      short8 b = *(const short8*)(hrow + kk * 32);
      acc[kk & 3] = __builtin_amdgcn_mfma_f32_16x16x32_bf16(a[kk], b, acc[kk & 3], 0, 0, 0);
    }
    float gi = acc[0][0] + acc[1][0] + acc[2][0] + acc[3][0] + bf2f(gv[0]);
    float gf = acc[0][1] + acc[1][1] + acc[2][1] + acc[3][1] + bf2f(gv[1]);
    float gg = acc[0][2] + acc[1][2] + acc[2][2] + acc[3][2] + bf2f(gv[2]);
    float go = acc[0][3] + acc[1][3] + acc[2][3] + acc[3][3] + bf2f(gv[3]);
    float i_ = sigmoidf_(gi);
    float f_ = sigmoidf_(gf);
    float g_ = tanhf(gg);
    float o_ = sigmoidf_(go);
    c = f_ * c + i_ * g_;
    float h = o_ * tanhf(c);
    hist[(size_t)(t & tmask) * 65536 + bat * 1024 + hid] = __float2bfloat16(h);
    if (y) y[(size_t)t * 65536 + bat * 1024 + hid] = h;
    if (t == 511) hf[bat * 1024 + hid] = h;

    if (t != 511) {
      __syncthreads();
      if (tid == 0) {
        unsigned tgt = (unsigned)(t + 1) * nb;
        __hip_atomic_fetch_add(ctr, 1u, __ATOMIC_RELEASE, __HIP_MEMORY_SCOPE_AGENT);
        while (__hip_atomic_load(ctr, __ATOMIC_RELAXED, __HIP_MEMORY_SCOPE_AGENT) < tgt)
          __builtin_amdgcn_s_sleep(1);
        // acquire load synchronizes-with every block's release add
        (void)__hip_atomic_load(ctr, __ATOMIC_ACQUIRE, __HIP_MEMORY_SCOPE_AGENT);
      }
      __syncthreads();
    }
  }
  cst[bat * 1024 + hid] = c;
}

// ---------------------------------------------------------------------------
extern "C" void kernel_launch(void* const* d_in, const int* in_sizes, int n_in,
                              void* d_out_, int out_size, void* d_ws, size_t ws_size,
                              hipStream_t stream) {
  (void)in_sizes; (void)n_in; (void)out_size; (void)ws_size;
  const float* x      = (const float*)d_in[0];
  const float* h0     = (const float*)d_in[1];
  const float* c0     = (const float*)d_in[2];
  const float* w_ih_0 = (const float*)d_in[3];
  const float* w_hh_0 = (const float*)d_in[4];
  const float* b_ih_0 = (const float*)d_in[5];
  const float* b_hh_0 = (const float*)d_in[6];
  const float* w_ih_1 = (const float*)d_in[7];
  const float* w_hh_1 = (const float*)d_in[8];
  const float* b_ih_1 = (const float*)d_in[9];
  const float* b_hh_1 = (const float*)d_in[10];
  float* out = (float*)d_out_;

  char* p = (char*)d_ws;
  auto alloc = [&](size_t bytes) { char* r = p; p += (bytes + 255) & ~(size_t)255; return r; };
  __hip_bfloat16* xb    = (__hip_bfloat16*)alloc(33554432);   // x bf16
  __hip_bfloat16* wbih0 = (__hip_bfloat16*)alloc(4194304);    // permuted
  __hip_bfloat16* wbhh0 = (__hip_bfloat16*)alloc(8388608);
  __hip_bfloat16* wbih1 = (__hip_bfloat16*)alloc(8388608);    // permuted
  __hip_bfloat16* wbhh1 = (__hip_bfloat16*)alloc(8388608);
  __hip_bfloat16* y0b   = (__hip_bfloat16*)alloc(67108864);   // layer-0 h history
  __hip_bfloat16* h1r   = (__hip_bfloat16*)alloc(262144);     // layer-1 h ring (2 slots)
  __hip_bfloat16* Gin   = (__hip_bfloat16*)alloc(268435456);  // [32768,4096]
  __hip_bfloat16* hinit = (__hip_bfloat16*)alloc(262144);     // [2][64][1024]
  float* bsum0          = (float*)alloc(16384);
  float* bsum1          = (float*)alloc(16384);
  float* cst            = (float*)alloc(524288);              // [2][64][1024]
  float* hf             = (float*)alloc(524288);
  unsigned* ctrs        = (unsigned*)alloc(512);

  // converts / init
  cvt_bf16<<<16777216 / 4 / 256, 256, 0, stream>>>(x, xb, 16777216 / 4);
  cvt_permrow<<<dim3(1, 4096), 256, 0, stream>>>(w_ih_0, wbih0, 512);
  cvt_bf16<<<4194304 / 4 / 256, 256, 0, stream>>>(w_hh_0, wbhh0, 4194304 / 4);
  cvt_permrow<<<dim3(1, 4096), 256, 0, stream>>>(w_ih_1, wbih1, 1024);
  cvt_bf16<<<4194304 / 4 / 256, 256, 0, stream>>>(w_hh_1, wbhh1, 4194304 / 4);
  bias_perm<<<16, 256, 0, stream>>>(b_ih_0, b_hh_0, bsum0);
  bias_perm<<<16, 256, 0, stream>>>(b_ih_1, b_hh_1, bsum1);
  init_state<<<131072 / 256, 256, 0, stream>>>(h0, c0, hinit, cst, 131072);
  (void)hipMemsetAsync(ctrs, 0, 512, stream);

  // layer 0: Gin = xb @ wbih0^T + bsum0 ; persistent recurrence
  gemm_bt_bias<<<dim3(256, 32), 256, 0, stream>>>(xb, wbih0, Gin, bsum0, 512, 4096);
  {
    const __hip_bfloat16* g_ = Gin;
    const __hip_bfloat16* w_ = wbhh0;
    const __hip_bfloat16* h_ = hinit;
    __hip_bfloat16* hist_ = y0b;
    int tmask_ = 511;
    float* c_ = cst;
    float* y_ = nullptr;
    float* hf_ = hf;
    unsigned* ctr_ = ctrs;
    void* args[] = {&g_, &w_, &h_, &hist_, &tmask_, &c_, &y_, &hf_, &ctr_};
    (void)hipLaunchCooperativeKernel((void*)lstm_persistent, dim3(128), dim3(512), args, 0, stream);
  }

  // layer 1: Gin = y0b @ wbih1^T + bsum1 ; persistent recurrence (y -> d_out f32)
  gemm_bt_bias<<<dim3(256, 32), 256, 0, stream>>>(y0b, wbih1, Gin, bsum1, 1024, 4096);
  {
    const __hip_bfloat16* g_ = Gin;
    const __hip_bfloat16* w_ = wbhh1;
    const __hip_bfloat16* h_ = hinit + 65536;
    __hip_bfloat16* hist_ = h1r;
    int tmask_ = 1;
    float* c_ = cst + 65536;
    float* y_ = out;
    float* hf_ = hf + 65536;
    unsigned* ctr_ = ctrs + 64;
    void* args[] = {&g_, &w_, &h_, &hist_, &tmask_, &c_, &y_, &hf_, &ctr_};
    (void)hipLaunchCooperativeKernel((void*)lstm_persistent, dim3(128), dim3(512), args, 0, stream);
  }

  finalize_out<<<131072 / 256, 256, 0, stream>>>(hf, cst, out + 33554432, out + 33685504, 131072);
}

// Round 4
// 10838.013 us; speedup vs baseline: 1.4026x; 1.4026x over previous
//
#include <hip/hip_runtime.h>
#include <hip/hip_bf16.h>
#include <cstdint>

// ---------------------------------------------------------------------------
// 2-layer LSTM, SEQ=512 B=64 IN=512 HID=1024.
// R4: persistent coop kernel, 64 blocks x 512 thr (1 block/CU).
//  - weights VGPR-pinned via asm (R3 failure: compiler sank them, VGPR=88)
//  - NO release/acquire in loop (R3: wbl2/buffer_inv per step per block).
//    h channel = sc0|sc1 stores/loads (coherent at LLC), vmcnt(0) drain via
//    __syncthreads, RELAXED group counters (8 groups of 8 blocks).
//  - h staged once/block into 128KB dynamic LDS, XOR-swizzled.
// ---------------------------------------------------------------------------

typedef __attribute__((ext_vector_type(8))) short short8;    // 8 bf16
typedef __attribute__((ext_vector_type(4))) short short4b;   // 4 bf16
typedef __attribute__((ext_vector_type(4))) float f32x4;

#define AS1 __attribute__((address_space(1)))
#define AS3 __attribute__((address_space(3)))

static __device__ __forceinline__ void gload_lds16(const void* g, void* l) {
  __builtin_amdgcn_global_load_lds((const AS1 unsigned int*)g, (AS3 unsigned int*)l,
                                   16, 0, 0);
}

static __device__ __forceinline__ float sigmoidf_(float x) {
  return 1.f / (1.f + __expf(-x));
}

static __device__ __forceinline__ float bf2f(short s) {
  union { unsigned u; float f; } v;
  v.u = ((unsigned)(unsigned short)s) << 16;
  return v.f;
}

static __device__ __forceinline__ unsigned f2bfbits(float f) {
  __hip_bfloat16 h = __float2bfloat16(f);
  union { __hip_bfloat16 h; unsigned short u; } v;
  v.h = h;
  return (unsigned)v.u;
}

// sc0|sc1 16B load: bypasses L1+L2, coherent at Infinity Cache.
static __device__ __forceinline__ f32x4 ld16_llc(const void* p) {
  f32x4 r;
  asm volatile("global_load_dwordx4 %0, %1, off sc0 sc1"
               : "=v"(r) : "v"(p) : "memory");
  return r;
}

// sc0|sc1 2B store straight to LLC.
static __device__ __forceinline__ void st2_llc(void* p, unsigned bits) {
  asm volatile("global_store_short %0, %1, off sc0 sc1"
               :: "v"(p), "v"(bits) : "memory");
}

// --------------------------- f32 -> bf16 convert ---------------------------
__global__ void cvt_bf16(const float* __restrict__ in, __hip_bfloat16* __restrict__ out,
                         int n4) {
  int i = blockIdx.x * 256 + threadIdx.x;
  if (i >= n4) return;
  float4 v = ((const float4*)in)[i];
  out[i * 4 + 0] = __float2bfloat16(v.x);
  out[i * 4 + 1] = __float2bfloat16(v.y);
  out[i * 4 + 2] = __float2bfloat16(v.z);
  out[i * 4 + 3] = __float2bfloat16(v.w);
}

// --------------- f32 -> bf16 with gate-row permutation ---------------------
// out[(hid*4+g)*K + k] = in[(g*1024+hid)*K + k]
__global__ void cvt_permrow(const float* __restrict__ in, __hip_bfloat16* __restrict__ out,
                            int K) {
  int k4 = blockIdx.x * 256 + threadIdx.x;
  if (k4 >= (K >> 2)) return;
  int rp = blockIdx.y;
  int src = (rp & 3) * 1024 + (rp >> 2);
  float4 v = ((const float4*)(in + (size_t)src * K))[k4];
  __hip_bfloat16* o = out + (size_t)rp * K + k4 * 4;
  o[0] = __float2bfloat16(v.x);
  o[1] = __float2bfloat16(v.y);
  o[2] = __float2bfloat16(v.z);
  o[3] = __float2bfloat16(v.w);
}

// ------------------ bias sum with gate-row permutation ---------------------
__global__ void bias_perm(const float* __restrict__ b1, const float* __restrict__ b2,
                          float* __restrict__ o) {
  int i = blockIdx.x * 256 + threadIdx.x;  // i = hid*4+g
  if (i >= 4096) return;
  int src = (i & 3) * 1024 + (i >> 2);
  o[i] = b1[src] + b2[src];
}

// ------------------------------ state init --------------------------------
__global__ void init_state(const float* __restrict__ h0, const float* __restrict__ c0,
                           __hip_bfloat16* __restrict__ h_init, float* __restrict__ c_state,
                           int n) {
  int i = blockIdx.x * 256 + threadIdx.x;
  if (i >= n) return;
  h_init[i] = __float2bfloat16(h0[i]);
  c_state[i] = c0[i];
}

// ------------------------------- finalize ---------------------------------
__global__ void finalize_out(const float* __restrict__ hf, const float* __restrict__ cst,
                             float* __restrict__ out_h, float* __restrict__ out_c, int n) {
  int i = blockIdx.x * 256 + threadIdx.x;
  if (i >= n) return;
  out_h[i] = hf[i];
  out_c[i] = cst[i];
}

// --------------------- big GEMM: C = A @ B^T + bias ------------------------
__global__ __launch_bounds__(256) void gemm_bt_bias(
    const __hip_bfloat16* __restrict__ A, const __hip_bfloat16* __restrict__ B,
    __hip_bfloat16* __restrict__ C, const float* __restrict__ bias, int K, int N) {
  const int tid = threadIdx.x;
  const int lane = tid & 63;
  const int wv = tid >> 6;
  const int l15 = lane & 15, l4 = lane >> 4;
  const int bm = blockIdx.x * 128;
  const int bn = blockIdx.y * 128;
  __shared__ alignas(16) __hip_bfloat16 As[128 * 64];
  __shared__ alignas(16) __hip_bfloat16 Bs[128 * 64];
  f32x4 acc[4][4] = {};
  const int wm = (wv >> 1) * 64;
  const int wn = (wv & 1) * 64;

  for (int kt = 0; kt < K; kt += 64) {
    if (kt) __syncthreads();
#pragma unroll
    for (int it = 0; it < 4; ++it) {
      int ci = it * 256 + tid;
      int row = ci >> 3, c8 = ci & 7;
      gload_lds16(A + (bm + row) * K + kt + c8 * 8, As + (it * 256 + wv * 64) * 8);
      gload_lds16(B + (bn + row) * K + kt + c8 * 8, Bs + (it * 256 + wv * 64) * 8);
    }
    __syncthreads();
#pragma unroll
    for (int kk = 0; kk < 64; kk += 32) {
      short8 a[4], b[4];
#pragma unroll
      for (int m = 0; m < 4; ++m)
        a[m] = *(const short8*)(As + (wm + m * 16 + l15) * 64 + kk + l4 * 8);
#pragma unroll
      for (int n = 0; n < 4; ++n)
        b[n] = *(const short8*)(Bs + (wn + n * 16 + l15) * 64 + kk + l4 * 8);
#pragma unroll
      for (int m = 0; m < 4; ++m)
#pragma unroll
        for (int n = 0; n < 4; ++n)
          acc[m][n] = __builtin_amdgcn_mfma_f32_16x16x32_bf16(a[m], b[n], acc[m][n], 0, 0, 0);
    }
  }
#pragma unroll
  for (int n = 0; n < 4; ++n) {
    int col = bn + wn + n * 16 + l15;
    float bs = bias[col];
#pragma unroll
    for (int m = 0; m < 4; ++m) {
#pragma unroll
      for (int j = 0; j < 4; ++j) {
        int row = bm + wm + m * 16 + l4 * 4 + j;
        C[(size_t)row * N + col] = __float2bfloat16(acc[m][n][j] + bs);
      }
    }
  }
}

// ----------------------- persistent LSTM layer kernel ----------------------
// 64 blocks x 512 thr. Block owns 16 hidden units (64 permuted gate-rows).
// Wave wv: rs = wv>>1 (row-strip of 16 rows = 4 hid x 4 gates), bh = wv&1
// (batch half). Each wave: A-strip in 128 pinned VGPRs, 2 batch-strips of 16,
// 64 MFMA/step. h staged to LDS once per block per step via sc1 loads.
__global__ __launch_bounds__(512, 2) void lstm_persistent(
    const __hip_bfloat16* __restrict__ Gin,   // [512][64][4096] gate-permuted
    const __hip_bfloat16* __restrict__ Whh,   // [4096][1024]
    const __hip_bfloat16* __restrict__ h0b,   // [64][1024] initial h
    __hip_bfloat16* __restrict__ hist,        // h ring/history, 65536 elems/t
    int tmask,                                // 511 = full history, 1 = ring
    float* __restrict__ cst,                  // [64][1024] c in/out
    float* __restrict__ y,                    // [512][64][1024] f32 or null
    float* __restrict__ hf,                   // [64][1024] final h f32
    unsigned* __restrict__ ctr) {             // 8 group counters, stride 32
  extern __shared__ char smem[];              // 131072 B h stage
  const int tid = threadIdx.x;
  const int lane = tid & 63;
  const int wv = tid >> 6;
  const int l15 = lane & 15, l4 = lane >> 4;
  const int rs = wv >> 1;
  const int bh = wv & 1;
  const int bbase = blockIdx.x * 16;
  const int hid = bbase + rs * 4 + l4;        // this lane's hidden unit

  // ---- load w_hh strip into registers and PIN it there ----
  const int grow = (l15 & 3) * 1024 + bbase + rs * 4 + (l15 >> 2);
  const __hip_bfloat16* wrow = Whh + (size_t)grow * 1024 + l4 * 8;
  short8 a[32];
#pragma unroll
  for (int kk = 0; kk < 32; ++kk)
    a[kk] = *(const short8*)(wrow + kk * 32);
#pragma unroll
  for (int kk = 0; kk < 32; ++kk)
    asm volatile("" : "+v"(a[kk]));  // opaque -> must stay resident

  float cS[2];
#pragma unroll
  for (int s = 0; s < 2; ++s)
    cS[s] = cst[(bh * 32 + s * 16 + l15) * 1024 + hid];

  for (int t = 0; t < 512; ++t) {
    // ---- stage h[t-1] (128KB) into LDS via LLC-coherent loads ----
    const char* hsrc = (const char*)(t ? hist + (size_t)((t - 1) & tmask) * 65536 : h0b);
    f32x4 tmp[16];
#pragma unroll
    for (int i = 0; i < 16; ++i)
      tmp[i] = ld16_llc(hsrc + (size_t)(i * 512 + tid) * 16);
    asm volatile("s_waitcnt vmcnt(0)" ::: "memory");
#pragma unroll
    for (int i = 0; i < 16; ++i) {
      int byteoff = (i * 512 + tid) * 16;
      int row = byteoff >> 11;                       // batch row (2048 B each)
      *(f32x4*)(smem + (byteoff ^ ((row & 7) << 4))) = tmp[i];
    }
    // Gin preactivations (independent of h) — issue now, consume in epilogue
    short4b gv[2];
#pragma unroll
    for (int s = 0; s < 2; ++s)
      gv[s] = *(const short4b*)(Gin + (size_t)t * 262144 +
                                (bh * 32 + s * 16 + l15) * 4096 + hid * 4);
    __syncthreads();

    // ---- gates = Whh_strip @ h^T : 64 MFMA, B-frags from swizzled LDS ----
    f32x4 acc[2][4] = {};
#pragma unroll
    for (int kk = 0; kk < 32; ++kk) {
      int ko = (kk * 32 + l4 * 8) * 2;               // byte offset in row
#pragma unroll
      for (int s = 0; s < 2; ++s) {
        int bat = bh * 32 + s * 16 + l15;
        short8 b = *(const short8*)(smem + ((bat * 2048 + ko) ^ ((bat & 7) << 4)));
        acc[s][kk & 3] =
            __builtin_amdgcn_mfma_f32_16x16x32_bf16(a[kk], b, acc[s][kk & 3], 0, 0, 0);
      }
    }

    // ---- epilogue: lane-local cell update for 2 (hid, bat) pairs ----
    __hip_bfloat16* hdst = hist + (size_t)(t & tmask) * 65536;
#pragma unroll
    for (int s = 0; s < 2; ++s) {
      int bat = bh * 32 + s * 16 + l15;
      float gi = acc[s][0][0] + acc[s][1][0] + acc[s][2][0] + acc[s][3][0] + bf2f(gv[s][0]);
      float gf = acc[s][0][1] + acc[s][1][1] + acc[s][2][1] + acc[s][3][1] + bf2f(gv[s][1]);
      float gg = acc[s][0][2] + acc[s][1][2] + acc[s][2][2] + acc[s][3][2] + bf2f(gv[s][2]);
      float go = acc[s][0][3] + acc[s][1][3] + acc[s][2][3] + acc[s][3][3] + bf2f(gv[s][3]);
      float i_ = sigmoidf_(gi);
      float f_ = sigmoidf_(gf);
      float g_ = tanhf(gg);
      float o_ = sigmoidf_(go);
      cS[s] = f_ * cS[s] + i_ * g_;
      float h = o_ * tanhf(cS[s]);
      st2_llc(hdst + bat * 1024 + hid, f2bfbits(h));  // LLC-visible h
      if (y) y[(size_t)t * 65536 + bat * 1024 + hid] = h;
      if (t == 511) hf[bat * 1024 + hid] = h;
    }

    // ---- grid barrier: NO cache maintenance, relaxed group counters ----
    if (t != 511) {
      __syncthreads();  // drains each wave's vmcnt(0) -> h stores at LLC
      if (tid == 0)
        __hip_atomic_fetch_add(ctr + (blockIdx.x >> 3) * 32, 1u,
                               __ATOMIC_RELAXED, __HIP_MEMORY_SCOPE_AGENT);
      if (tid < 8) {
        unsigned tgt = (unsigned)(t + 1) * 8u;
        while (__hip_atomic_load(ctr + tid * 32, __ATOMIC_RELAXED,
                                 __HIP_MEMORY_SCOPE_AGENT) < tgt)
          __builtin_amdgcn_s_sleep(4);
      }
      __syncthreads();
      asm volatile("" ::: "memory");
    }
  }
#pragma unroll
  for (int s = 0; s < 2; ++s)
    cst[(bh * 32 + s * 16 + l15) * 1024 + hid] = cS[s];
}

// ---------------------------------------------------------------------------
extern "C" void kernel_launch(void* const* d_in, const int* in_sizes, int n_in,
                              void* d_out_, int out_size, void* d_ws, size_t ws_size,
                              hipStream_t stream) {
  (void)in_sizes; (void)n_in; (void)out_size; (void)ws_size;
  const float* x      = (const float*)d_in[0];
  const float* h0     = (const float*)d_in[1];
  const float* c0     = (const float*)d_in[2];
  const float* w_ih_0 = (const float*)d_in[3];
  const float* w_hh_0 = (const float*)d_in[4];
  const float* b_ih_0 = (const float*)d_in[5];
  const float* b_hh_0 = (const float*)d_in[6];
  const float* w_ih_1 = (const float*)d_in[7];
  const float* w_hh_1 = (const float*)d_in[8];
  const float* b_ih_1 = (const float*)d_in[9];
  const float* b_hh_1 = (const float*)d_in[10];
  float* out = (float*)d_out_;

  char* p = (char*)d_ws;
  auto alloc = [&](size_t bytes) { char* r = p; p += (bytes + 255) & ~(size_t)255; return r; };
  __hip_bfloat16* xb    = (__hip_bfloat16*)alloc(33554432);
  __hip_bfloat16* wbih0 = (__hip_bfloat16*)alloc(4194304);
  __hip_bfloat16* wbhh0 = (__hip_bfloat16*)alloc(8388608);
  __hip_bfloat16* wbih1 = (__hip_bfloat16*)alloc(8388608);
  __hip_bfloat16* wbhh1 = (__hip_bfloat16*)alloc(8388608);
  __hip_bfloat16* y0b   = (__hip_bfloat16*)alloc(67108864);   // layer-0 h history
  __hip_bfloat16* h1r   = (__hip_bfloat16*)alloc(262144);     // layer-1 2-slot ring
  __hip_bfloat16* Gin   = (__hip_bfloat16*)alloc(268435456);  // shared by both layers
  __hip_bfloat16* hinit = (__hip_bfloat16*)alloc(262144);
  float* bsum0          = (float*)alloc(16384);
  float* bsum1          = (float*)alloc(16384);
  float* cst            = (float*)alloc(524288);
  float* hf             = (float*)alloc(524288);
  unsigned* ctrs        = (unsigned*)alloc(2048);

  (void)hipFuncSetAttribute((const void*)lstm_persistent,
                            hipFuncAttributeMaxDynamicSharedMemorySize, 131072);

  cvt_bf16<<<16777216 / 4 / 256, 256, 0, stream>>>(x, xb, 16777216 / 4);
  cvt_permrow<<<dim3(1, 4096), 256, 0, stream>>>(w_ih_0, wbih0, 512);
  cvt_bf16<<<4194304 / 4 / 256, 256, 0, stream>>>(w_hh_0, wbhh0, 4194304 / 4);
  cvt_permrow<<<dim3(1, 4096), 256, 0, stream>>>(w_ih_1, wbih1, 1024);
  cvt_bf16<<<4194304 / 4 / 256, 256, 0, stream>>>(w_hh_1, wbhh1, 4194304 / 4);
  bias_perm<<<16, 256, 0, stream>>>(b_ih_0, b_hh_0, bsum0);
  bias_perm<<<16, 256, 0, stream>>>(b_ih_1, b_hh_1, bsum1);
  init_state<<<131072 / 256, 256, 0, stream>>>(h0, c0, hinit, cst, 131072);
  (void)hipMemsetAsync(ctrs, 0, 2048, stream);

  // layer 0
  gemm_bt_bias<<<dim3(256, 32), 256, 0, stream>>>(xb, wbih0, Gin, bsum0, 512, 4096);
  {
    const __hip_bfloat16* g_ = Gin;
    const __hip_bfloat16* w_ = wbhh0;
    const __hip_bfloat16* h_ = hinit;
    __hip_bfloat16* hist_ = y0b;
    int tmask_ = 511;
    float* c_ = cst;
    float* y_ = nullptr;
    float* hf_ = hf;
    unsigned* ctr_ = ctrs;
    void* args[] = {&g_, &w_, &h_, &hist_, &tmask_, &c_, &y_, &hf_, &ctr_};
    (void)hipLaunchCooperativeKernel((void*)lstm_persistent, dim3(64), dim3(512),
                                     args, 131072, stream);
  }

  // layer 1
  gemm_bt_bias<<<dim3(256, 32), 256, 0, stream>>>(y0b, wbih1, Gin, bsum1, 1024, 4096);
  {
    const __hip_bfloat16* g_ = Gin;
    const __hip_bfloat16* w_ = wbhh1;
    const __hip_bfloat16* h_ = hinit + 65536;
    __hip_bfloat16* hist_ = h1r;
    int tmask_ = 1;
    float* c_ = cst + 65536;
    float* y_ = out;
    float* hf_ = hf + 65536;
    unsigned* ctr_ = ctrs + 256;
    void* args[] = {&g_, &w_, &h_, &hist_, &tmask_, &c_, &y_, &hf_, &ctr_};
    (void)hipLaunchCooperativeKernel((void*)lstm_persistent, dim3(64), dim3(512),
                                     args, 131072, stream);
  }

  finalize_out<<<131072 / 256, 256, 0, stream>>>(hf, cst, out + 33554432, out + 33685504, 131072);
}